// Round 10
// baseline (187.000 us; speedup 1.0000x reference)
//
#include <hip/hip_runtime.h>
#include <hip/hip_fp16.h>
#include <math.h>

#define NFEAT 128
#define NHID  128
#define ALPHA 0.2f

typedef __attribute__((ext_vector_type(8))) short short8;
typedef __attribute__((ext_vector_type(4))) float f32x4;

__device__ inline unsigned int pack_bf16x2_rn(float x, float y) {
    unsigned int bx = __float_as_uint(x), by = __float_as_uint(y);
    bx += 0x7fffu + ((bx >> 16) & 1u);
    by += 0x7fffu + ((by >> 16) & 1u);
    return (bx >> 16) | (by & 0xffff0000u);
}

union Frag { unsigned int u[4]; uint4 v; short8 s; };

// ---------------------------------------------------------------------------
// prep_wt + hist-zero fused. Blocks [0,16): transpose W -> bf16 Wt (32 KB).
// Blocks >=16: zero hist[n] with grid-stride int4 stores.
// ---------------------------------------------------------------------------
__global__ __launch_bounds__(256) void prep_wt_kernel(
    const float* __restrict__ W, unsigned int* __restrict__ Wtg,
    int* __restrict__ hist, int n)
{
    const int t = threadIdx.x;

    if (blockIdx.x >= 16) {
        const int n4     = n >> 2;
        const int stride = (gridDim.x - 16) << 8;
        int4* h4 = (int4*)hist;
        for (int i = (blockIdx.x - 16) * 256 + t; i < n4; i += stride)
            h4[i] = make_int4(0, 0, 0, 0);
        for (int i = (n4 << 2) + (blockIdx.x - 16) * 256 + t; i < n; i += stride)
            hist[i] = 0;
        return;
    }

    __shared__ float tile[32][33];
    const int kt = blockIdx.x >> 2;
    const int nt = blockIdx.x & 3;

    {
        const int r = t >> 3, c = t & 7;
        const float4 v = *((const float4*)&W[(size_t)(kt * 32 + r) * NHID + nt * 32 + c * 4]);
        tile[r][c * 4 + 0] = v.x; tile[r][c * 4 + 1] = v.y;
        tile[r][c * 4 + 2] = v.z; tile[r][c * 4 + 3] = v.w;
    }
    __syncthreads();

    const int nn = t & 31;
    #pragma unroll
    for (int i = 0; i < 2; ++i) {
        const int kk = (t >> 5) * 2 + i;
        Wtg[(size_t)(nt * 32 + nn) * 64 + kt * 16 + kk] =
            pack_bf16x2_rn(tile[kk * 2][nn], tile[kk * 2 + 1][nn]);
    }
}

// ---------------------------------------------------------------------------
// Histogram (standalone): 4 edges/thread, fire-and-forget device atomics.
// ---------------------------------------------------------------------------
__global__ __launch_bounds__(256) void hist_kernel(
    const int* __restrict__ ei, int* __restrict__ hist, int E)
{
    const int j0 = (blockIdx.x * 256 + threadIdx.x) * 4;
    if (j0 + 4 <= E) {
        const int4 s4 = *((const int4*)(ei + j0));
        atomicAdd(&hist[s4.x], 1);
        atomicAdd(&hist[s4.y], 1);
        atomicAdd(&hist[s4.z], 1);
        atomicAdd(&hist[s4.w], 1);
    } else {
        for (int j = j0; j < E; ++j) atomicAdd(&hist[ei[j]], 1);
    }
}

__global__ __launch_bounds__(256) void scan_block_kernel(
    const int* __restrict__ in, int* __restrict__ out, int* __restrict__ bsums, int n)
{
    __shared__ int s[256];
    const int tid = threadIdx.x;
    const int gid = blockIdx.x * 256 + tid;
    const int v = (gid < n) ? in[gid] : 0;
    s[tid] = v;
    __syncthreads();
    #pragma unroll
    for (int off = 1; off < 256; off <<= 1) {
        const int t2 = (tid >= off) ? s[tid - off] : 0;
        __syncthreads();
        s[tid] += t2;
        __syncthreads();
    }
    if (gid < n) out[gid] = s[tid] - v;
    if (tid == 255) bsums[blockIdx.x] = s[255];
}

// Fused level-2 scan + add (nb <= 256): every block scans bsums in LDS.
__global__ __launch_bounds__(256) void scan_add_kernel(
    int* __restrict__ row_ptr, int* __restrict__ cursor,
    const int* __restrict__ bsums, int n, int E, int nb)
{
    __shared__ int s[256];
    const int tid = threadIdx.x;
    s[tid] = (tid < nb) ? bsums[tid] : 0;
    __syncthreads();
    #pragma unroll
    for (int off = 1; off < 256; off <<= 1) {
        const int t2 = (tid >= off) ? s[tid - off] : 0;
        __syncthreads();
        s[tid] += t2;
        __syncthreads();
    }
    const int offset = (blockIdx.x == 0) ? 0 : s[blockIdx.x - 1];
    const int gid = blockIdx.x * 256 + tid;
    if (gid < n) {
        const int v = row_ptr[gid] + offset;
        row_ptr[gid] = v;
        cursor[gid]  = v;
    }
    if (gid == 0) row_ptr[n] = E;
}

// ---------------------------------------------------------------------------
// MFMA bf16 GEMM + fused CSR scatter (block-specialized).
// GEMM blocks: 64 rows/block, 16 rows/wave, A in registers, B XOR-swizzled LDS.
// Scatter blocks: grid-stride over edges; 2-byte records (ushort dst) —
// ev is computed later in aggregate, so no s1/s2 dependency here.
// ---------------------------------------------------------------------------
__global__ __launch_bounds__(256) void gemm_h_kernel(
    const float* __restrict__ x, const unsigned int* __restrict__ Wtg,
    const float* __restrict__ a, float* __restrict__ h,
    unsigned int* __restrict__ hbu,
    float* __restrict__ s1, float* __restrict__ s2, int n,
    const int* __restrict__ ei, int* __restrict__ cursor,
    unsigned short* __restrict__ erec16, int E, int gemm_blocks)
{
    __shared__ unsigned int Wtu[128 * 64];   // 32 KB

    const int t = threadIdx.x;

    if (blockIdx.x >= gemm_blocks) {
        const int nthr = (gridDim.x - gemm_blocks) << 8;
        const int g    = (blockIdx.x - gemm_blocks) * 256 + t;
        for (int j = g; j < E; j += nthr) {
            const int src = ei[j];
            const int dst = ei[E + j];
            const int pos = atomicAdd(&cursor[src], 1);
            erec16[pos] = (unsigned short)dst;
        }
        return;
    }

    #pragma unroll
    for (int i = 0; i < 8; ++i) {
        const int u  = i * 256 + t;
        const uint4 v = ((const uint4*)Wtg)[u];
        const int nn = u >> 4, kc = u & 15;
        *((uint4*)&Wtu[nn * 64 + (kc ^ (nn & 15)) * 4]) = v;
    }

    const int w    = t >> 6;
    const int lane = t & 63;
    const int c    = lane & 15;
    const int quad = lane >> 4;

    const int rowbase = blockIdx.x * 64 + w * 16;

    int arow = rowbase + c; if (arow >= n) arow = n - 1;
    const float4* xp = (const float4*)(x + (size_t)arow * NFEAT);
    float4 xv[8];
    #pragma unroll
    for (int s = 0; s < 4; ++s) {
        xv[2 * s]     = xp[s * 8 + quad * 2];
        xv[2 * s + 1] = xp[s * 8 + quad * 2 + 1];
    }

    float a1v[8], a2v[8];
    #pragma unroll
    for (int tt = 0; tt < 8; ++tt) {
        a1v[tt] = a[tt * 16 + c];
        a2v[tt] = a[NHID + tt * 16 + c];
    }

    f32x4 acc[8];
    #pragma unroll
    for (int tt = 0; tt < 8; ++tt) acc[tt] = (f32x4){0.f, 0.f, 0.f, 0.f};

    __syncthreads();

    #pragma unroll
    for (int s = 0; s < 4; ++s) {
        Frag afr;
        afr.u[0] = pack_bf16x2_rn(xv[2 * s].x,     xv[2 * s].y);
        afr.u[1] = pack_bf16x2_rn(xv[2 * s].z,     xv[2 * s].w);
        afr.u[2] = pack_bf16x2_rn(xv[2 * s + 1].x, xv[2 * s + 1].y);
        afr.u[3] = pack_bf16x2_rn(xv[2 * s + 1].z, xv[2 * s + 1].w);
        const int kc = s * 4 + quad;
        #pragma unroll
        for (int tt = 0; tt < 8; ++tt) {
            Frag bfr;
            bfr.v = *((const uint4*)&Wtu[(tt * 16 + c) * 64 + (kc ^ c) * 4]);
            acc[tt] = __builtin_amdgcn_mfma_f32_16x16x32_bf16(
                afr.s, bfr.s, acc[tt], 0, 0, 0);
        }
    }

    #pragma unroll
    for (int r = 0; r < 4; ++r) {
        const int  row = rowbase + quad * 4 + r;
        const bool ok  = (row < n);
        float p1 = 0.f, p2 = 0.f;
        #pragma unroll
        for (int tt = 0; tt < 8; ++tt) {
            const float v = acc[tt][r];
            if (ok) h[(size_t)row * NHID + tt * 16 + c] = v;
            p1 = fmaf(v, a1v[tt], p1);
            p2 = fmaf(v, a2v[tt], p2);
        }
        #pragma unroll
        for (int p = 0; p < 4; ++p) {
            if (ok) hbu[(size_t)row * 64 + p * 16 + c] =
                pack_bf16x2_rn(acc[2 * p][r], acc[2 * p + 1][r]);
        }
        #pragma unroll
        for (int off = 1; off <= 8; off <<= 1) {
            p1 += __shfl_xor(p1, off, 64);
            p2 += __shfl_xor(p2, off, 64);
        }
        if (ok && c == 0) { s1[row] = p1; s2[row] = p2; }
    }
}

// ---------------------------------------------------------------------------
// Aggregate + finalize: 16-lane group per node, masked 8-deep batches.
// ev computed on the fly: ev = exp(-leaky(s1[node] + s2[dst])); invalid
// slots masked to ev = 0 exactly. hbu dword (p*16+c) = pack(col 32p+c,
// col 32p+16+c).
// ---------------------------------------------------------------------------
__global__ __launch_bounds__(256) void aggregate_kernel(
    const int* __restrict__ row_ptr, const unsigned short* __restrict__ erec16,
    const float* __restrict__ s1, const float* __restrict__ s2,
    const unsigned int* __restrict__ hbu, const float* __restrict__ h,
    float* __restrict__ out, int n)
{
    const int node = (blockIdx.x * 256 + threadIdx.x) >> 4;
    const int l    = threadIdx.x & 15;
    if (node >= n) return;

    const int beg = row_ptr[node];
    const int end = row_ptr[node + 1];
    const float s1v = s1[node];

    float acc[8];
    #pragma unroll
    for (int i = 0; i < 8; ++i) acc[i] = 0.f;
    float rs = 0.f;

    const uint4* hbu4 = (const uint4*)hbu;

    #define BL(x) __uint_as_float((x) << 16)
    #define BH(x) __uint_as_float((x) & 0xffff0000u)
    #define ACC4(u, ev)                                   \
        acc[0] = fmaf(ev, BL(u.x), acc[0]);               \
        acc[4] = fmaf(ev, BH(u.x), acc[4]);               \
        acc[1] = fmaf(ev, BL(u.y), acc[1]);               \
        acc[5] = fmaf(ev, BH(u.y), acc[5]);               \
        acc[2] = fmaf(ev, BL(u.z), acc[2]);               \
        acc[6] = fmaf(ev, BH(u.z), acc[6]);               \
        acc[3] = fmaf(ev, BL(u.w), acc[3]);               \
        acc[7] = fmaf(ev, BH(u.w), acc[7]);

    for (int b = beg; b < end; b += 8) {
        int dst[8];
        #pragma unroll
        for (int j = 0; j < 8; ++j) {
            const int idx = (b + j < end) ? b + j : beg;   // safe addr
            dst[j] = erec16[idx];
        }
        float s2v[8];
        #pragma unroll
        for (int j = 0; j < 8; ++j) s2v[j] = s2[dst[j]];
        uint4 u[8];
        #pragma unroll
        for (int j = 0; j < 8; ++j) u[j] = hbu4[(size_t)dst[j] * 16 + l];
        #pragma unroll
        for (int j = 0; j < 8; ++j) {
            float s = s1v + s2v[j];
            s = (s > 0.f) ? s : ALPHA * s;
            float ev = expf(-s);
            ev = (b + j < end) ? ev : 0.f;
            ACC4(u[j], ev);
            rs += ev;
        }
    }
    #undef ACC4
    #undef BL
    #undef BH

    const float rinv = 1.0f / (rs + 1e-16f);
    const int p = l >> 2, q = l & 3;
    const float4* hp4 = (const float4*)(h + (size_t)node * NHID);
    const float4 ha = hp4[8 * p + q];
    const float4 hb = hp4[8 * p + 4 + q];
    float4 oa, ob;
    float z;
    z = ha.x - acc[0] * rinv; oa.x = (z > 0.f) ? z : (expf(z) - 1.f);
    z = ha.y - acc[1] * rinv; oa.y = (z > 0.f) ? z : (expf(z) - 1.f);
    z = ha.z - acc[2] * rinv; oa.z = (z > 0.f) ? z : (expf(z) - 1.f);
    z = ha.w - acc[3] * rinv; oa.w = (z > 0.f) ? z : (expf(z) - 1.f);
    z = hb.x - acc[4] * rinv; ob.x = (z > 0.f) ? z : (expf(z) - 1.f);
    z = hb.y - acc[5] * rinv; ob.y = (z > 0.f) ? z : (expf(z) - 1.f);
    z = hb.z - acc[6] * rinv; ob.z = (z > 0.f) ? z : (expf(z) - 1.f);
    z = hb.w - acc[7] * rinv; ob.w = (z > 0.f) ? z : (expf(z) - 1.f);
    float4* op = (float4*)(out + (size_t)node * NHID);
    op[8 * p + q]     = oa;
    op[8 * p + 4 + q] = ob;
}

// ---------------------------------------------------------------------------
extern "C" void kernel_launch(void* const* d_in, const int* in_sizes, int n_in,
                              void* d_out, int out_size, void* d_ws, size_t ws_size,
                              hipStream_t stream) {
    const float* x  = (const float*)d_in[0];
    const float* W  = (const float*)d_in[1];
    const float* a  = (const float*)d_in[2];
    const int*   ei = (const int*)d_in[3];

    const int n = in_sizes[0] / NFEAT;   // 50000
    const int E = in_sizes[3] / 2;       // 640000
    const int nb = (n + 255) / 256;      // 196 (<= 256)

    float* out = (float*)d_out;

    // Workspace (4-byte units):
    //   h[n*128] | hbu[n*64] | s1[n] | s2[n] | erec16[E ushort] | Wtg[8192] |
    //   hist[n] | bsums[256] | row_ptr[n+1] | cursor[n]
    float*          h      = (float*)d_ws;
    unsigned int*   hbu    = (unsigned int*)(h + (size_t)n * NHID);
    float*          s1     = (float*)(hbu + (size_t)n * 64);
    float*          s2     = s1 + n;
    unsigned short* erec16 = (unsigned short*)(s2 + n);
    unsigned int*   Wtg    = (unsigned int*)(erec16 + ((E + 1) & ~1));
    int*            hist   = (int*)(Wtg + 8192);
    int*            bsums  = hist + n;
    int*            row_ptr = bsums + 256;
    int*            cursor  = row_ptr + (n + 1);

    // 1) W transpose + hist zero (independent halves of the grid).
    prep_wt_kernel<<<16 + 50, 256, 0, stream>>>(W, Wtg, hist, n);

    // 2) histogram.
    hist_kernel<<<(E / 4 + 255) / 256, 256, 0, stream>>>(ei, hist, E);

    // 3) per-block scan, 4) fused level-2 scan + add (cursor init).
    scan_block_kernel<<<nb, 256, 0, stream>>>(hist, row_ptr, bsums, n);
    scan_add_kernel<<<nb, 256, 0, stream>>>(row_ptr, cursor, bsums, n, E, nb);

    // 5) GEMM + fused 2-byte CSR scatter (block-specialized, independent).
    const int gemm_blocks    = (n + 63) / 64;   // 782
    const int scatter_blocks = 512;
    gemm_h_kernel<<<gemm_blocks + scatter_blocks, 256, 0, stream>>>(
        x, Wtg, a, h, hbu, s1, s2, n, ei, cursor, erec16, E, gemm_blocks);

    // 6) gather-aggregate + finalize (ev computed on the fly).
    aggregate_kernel<<<((size_t)n * 16 + 255) / 256, 256, 0, stream>>>(
        row_ptr, erec16, s1, s2, hbu, h, out, n);
}

// Round 11
// 175.970 us; speedup vs baseline: 1.0627x; 1.0627x over previous
//
#include <hip/hip_runtime.h>
#include <hip/hip_fp16.h>
#include <math.h>

#define NFEAT 128
#define NHID  128
#define ALPHA 0.2f

typedef __attribute__((ext_vector_type(8))) short short8;
typedef __attribute__((ext_vector_type(4))) float f32x4;

__device__ inline unsigned int pack_bf16x2_rn(float x, float y) {
    unsigned int bx = __float_as_uint(x), by = __float_as_uint(y);
    bx += 0x7fffu + ((bx >> 16) & 1u);
    by += 0x7fffu + ((by >> 16) & 1u);
    return (bx >> 16) | (by & 0xffff0000u);
}

union Frag { unsigned int u[4]; uint4 v; short8 s; };

// ---------------------------------------------------------------------------
// prep_wt + hist-zero fused. Blocks [0,16): transpose W -> bf16 Wt (32 KB).
// Blocks >=16: zero hist[n] with grid-stride int4 stores.
// ---------------------------------------------------------------------------
__global__ __launch_bounds__(256) void prep_wt_kernel(
    const float* __restrict__ W, unsigned int* __restrict__ Wtg,
    int* __restrict__ hist, int n)
{
    const int t = threadIdx.x;

    if (blockIdx.x >= 16) {
        const int n4     = n >> 2;
        const int stride = (gridDim.x - 16) << 8;
        int4* h4 = (int4*)hist;
        for (int i = (blockIdx.x - 16) * 256 + t; i < n4; i += stride)
            h4[i] = make_int4(0, 0, 0, 0);
        for (int i = (n4 << 2) + (blockIdx.x - 16) * 256 + t; i < n; i += stride)
            hist[i] = 0;
        return;
    }

    __shared__ float tile[32][33];
    const int kt = blockIdx.x >> 2;
    const int nt = blockIdx.x & 3;

    {
        const int r = t >> 3, c = t & 7;
        const float4 v = *((const float4*)&W[(size_t)(kt * 32 + r) * NHID + nt * 32 + c * 4]);
        tile[r][c * 4 + 0] = v.x; tile[r][c * 4 + 1] = v.y;
        tile[r][c * 4 + 2] = v.z; tile[r][c * 4 + 3] = v.w;
    }
    __syncthreads();

    const int nn = t & 31;
    #pragma unroll
    for (int i = 0; i < 2; ++i) {
        const int kk = (t >> 5) * 2 + i;
        Wtg[(size_t)(nt * 32 + nn) * 64 + kt * 16 + kk] =
            pack_bf16x2_rn(tile[kk * 2][nn], tile[kk * 2 + 1][nn]);
    }
}

// ---------------------------------------------------------------------------
// MFMA bf16 GEMM + fused edge histogram (block-specialized, R8 structure).
// GEMM: 64 rows/block, 16 rows/wave, A prefetched to registers, B in
// XOR-swizzled LDS. NO fp32 h output: bf16 hbu only, one uint4 store/row.
// hbu layout: dword (c*4+p) of a row = pack(col 32p+c, col 32p+16+c).
// ---------------------------------------------------------------------------
__global__ __launch_bounds__(256) void gemm_h_kernel(
    const float* __restrict__ x, const unsigned int* __restrict__ Wtg,
    const float* __restrict__ a, unsigned int* __restrict__ hbu,
    float* __restrict__ s1, float* __restrict__ s2, int n,
    const int* __restrict__ ei, int* __restrict__ hist, int E, int gemm_blocks)
{
    __shared__ unsigned int Wtu[128 * 64];   // 32 KB

    const int t = threadIdx.x;

    if (blockIdx.x >= gemm_blocks) {
        // ---- histogram-only blocks ----
        const int E4   = E >> 2;
        const int nthr = (gridDim.x - gemm_blocks) << 8;
        const int g    = (blockIdx.x - gemm_blocks) * 256 + t;
        for (int idx = g; idx < E4; idx += nthr) {
            const int4 s4 = ((const int4*)ei)[idx];
            atomicAdd(&hist[s4.x], 1);
            atomicAdd(&hist[s4.y], 1);
            atomicAdd(&hist[s4.z], 1);
            atomicAdd(&hist[s4.w], 1);
        }
        for (int j = (E4 << 2) + g; j < E; j += nthr) atomicAdd(&hist[ei[j]], 1);
        return;
    }

    #pragma unroll
    for (int i = 0; i < 8; ++i) {
        const int u  = i * 256 + t;
        const uint4 v = ((const uint4*)Wtg)[u];
        const int nn = u >> 4, kc = u & 15;
        *((uint4*)&Wtu[nn * 64 + (kc ^ (nn & 15)) * 4]) = v;
    }

    const int w    = t >> 6;
    const int lane = t & 63;
    const int c    = lane & 15;
    const int quad = lane >> 4;

    const int rowbase = blockIdx.x * 64 + w * 16;

    int arow = rowbase + c; if (arow >= n) arow = n - 1;
    const float4* xp = (const float4*)(x + (size_t)arow * NFEAT);
    float4 xv[8];
    #pragma unroll
    for (int s = 0; s < 4; ++s) {
        xv[2 * s]     = xp[s * 8 + quad * 2];
        xv[2 * s + 1] = xp[s * 8 + quad * 2 + 1];
    }

    float a1v[8], a2v[8];
    #pragma unroll
    for (int tt = 0; tt < 8; ++tt) {
        a1v[tt] = a[tt * 16 + c];
        a2v[tt] = a[NHID + tt * 16 + c];
    }

    f32x4 acc[8];
    #pragma unroll
    for (int tt = 0; tt < 8; ++tt) acc[tt] = (f32x4){0.f, 0.f, 0.f, 0.f};

    __syncthreads();

    #pragma unroll
    for (int s = 0; s < 4; ++s) {
        Frag afr;
        afr.u[0] = pack_bf16x2_rn(xv[2 * s].x,     xv[2 * s].y);
        afr.u[1] = pack_bf16x2_rn(xv[2 * s].z,     xv[2 * s].w);
        afr.u[2] = pack_bf16x2_rn(xv[2 * s + 1].x, xv[2 * s + 1].y);
        afr.u[3] = pack_bf16x2_rn(xv[2 * s + 1].z, xv[2 * s + 1].w);
        const int kc = s * 4 + quad;
        #pragma unroll
        for (int tt = 0; tt < 8; ++tt) {
            Frag bfr;
            bfr.v = *((const uint4*)&Wtu[(tt * 16 + c) * 64 + (kc ^ c) * 4]);
            acc[tt] = __builtin_amdgcn_mfma_f32_16x16x32_bf16(
                afr.s, bfr.s, acc[tt], 0, 0, 0);
        }
    }

    // Epilogue: one uint4 hbu store per r, plus s1/s2 16-lane reductions.
    #pragma unroll
    for (int r = 0; r < 4; ++r) {
        const int  row = rowbase + quad * 4 + r;
        const bool ok  = (row < n);
        float p1 = 0.f, p2 = 0.f;
        #pragma unroll
        for (int tt = 0; tt < 8; ++tt) {
            const float v = acc[tt][r];
            p1 = fmaf(v, a1v[tt], p1);
            p2 = fmaf(v, a2v[tt], p2);
        }
        if (ok) {
            uint4 pk;
            pk.x = pack_bf16x2_rn(acc[0][r], acc[1][r]);
            pk.y = pack_bf16x2_rn(acc[2][r], acc[3][r]);
            pk.z = pack_bf16x2_rn(acc[4][r], acc[5][r]);
            pk.w = pack_bf16x2_rn(acc[6][r], acc[7][r]);
            *((uint4*)&hbu[(size_t)row * 64 + c * 4]) = pk;
        }
        #pragma unroll
        for (int off = 1; off <= 8; off <<= 1) {
            p1 += __shfl_xor(p1, off, 64);
            p2 += __shfl_xor(p2, off, 64);
        }
        if (ok && c == 0) { s1[row] = p1; s2[row] = p2; }
    }
}

__global__ __launch_bounds__(256) void scan_block_kernel(
    const int* __restrict__ in, int* __restrict__ out, int* __restrict__ bsums, int n)
{
    __shared__ int s[256];
    const int tid = threadIdx.x;
    const int gid = blockIdx.x * 256 + tid;
    const int v = (gid < n) ? in[gid] : 0;
    s[tid] = v;
    __syncthreads();
    #pragma unroll
    for (int off = 1; off < 256; off <<= 1) {
        const int t2 = (tid >= off) ? s[tid - off] : 0;
        __syncthreads();
        s[tid] += t2;
        __syncthreads();
    }
    if (gid < n) out[gid] = s[tid] - v;
    if (tid == 255) bsums[blockIdx.x] = s[255];
}

// Fused level-2 scan + add (nb <= 256).
__global__ __launch_bounds__(256) void scan_add_kernel(
    int* __restrict__ row_ptr, int* __restrict__ cursor,
    const int* __restrict__ bsums, int n, int E, int nb)
{
    __shared__ int s[256];
    const int tid = threadIdx.x;
    s[tid] = (tid < nb) ? bsums[tid] : 0;
    __syncthreads();
    #pragma unroll
    for (int off = 1; off < 256; off <<= 1) {
        const int t2 = (tid >= off) ? s[tid - off] : 0;
        __syncthreads();
        s[tid] += t2;
        __syncthreads();
    }
    const int offset = (blockIdx.x == 0) ? 0 : s[blockIdx.x - 1];
    const int gid = blockIdx.x * 256 + tid;
    if (gid < n) {
        const int v = row_ptr[gid] + offset;
        row_ptr[gid] = v;
        cursor[gid]  = v;
    }
    if (gid == 0) row_ptr[n] = E;
}

// ---------------------------------------------------------------------------
// Scatter: 1 edge/thread, 4-byte records (dst<<16 | fp16(ev)).
// ---------------------------------------------------------------------------
__global__ __launch_bounds__(256) void scatter_kernel(
    const int* __restrict__ ei, const float* __restrict__ s1,
    const float* __restrict__ s2, int* __restrict__ cursor,
    unsigned int* __restrict__ erec, int E)
{
    const int j = blockIdx.x * 256 + threadIdx.x;
    if (j >= E) return;
    const int src = ei[j];
    const int dst = ei[E + j];
    float s = s1[src] + s2[dst];
    s = (s > 0.f) ? s : ALPHA * s;
    const float ev = expf(-s);
    const unsigned int evh = (unsigned int)__half_as_ushort(__float2half(ev));
    const int pos = atomicAdd(&cursor[src], 1);
    erec[pos] = ((unsigned int)dst << 16) | evh;
}

// ---------------------------------------------------------------------------
// Aggregate + finalize: 16-lane group per node, 8/2/1 batches.
// hbu layout: dword (c*4+p) of a row = pack(col 32p+c, col 32p+16+c).
// Lane l reads uint4 at dwords 4l..4l+3 -> c=l, p=component:
//   acc[p]   <- col 32p+l    (BL),   acc[4+p] <- col 32p+16+l (BH).
// Finalize reads the node's OWN hbu row for the elu input (no fp32 h).
// ---------------------------------------------------------------------------
__global__ __launch_bounds__(256) void aggregate_kernel(
    const int* __restrict__ row_ptr, const unsigned int* __restrict__ erec,
    const unsigned int* __restrict__ hbu, float* __restrict__ out, int n)
{
    const int node = (blockIdx.x * 256 + threadIdx.x) >> 4;
    const int l    = threadIdx.x & 15;
    if (node >= n) return;

    const int beg = row_ptr[node];
    const int end = row_ptr[node + 1];

    float acc[8];
    #pragma unroll
    for (int i = 0; i < 8; ++i) acc[i] = 0.f;
    float rs = 0.f;

    const uint4* hbu4 = (const uint4*)hbu;

    #define BL(x) __uint_as_float((x) << 16)
    #define BH(x) __uint_as_float((x) & 0xffff0000u)
    #define ACC4(u, ev)                                   \
        acc[0] = fmaf(ev, BL(u.x), acc[0]);               \
        acc[4] = fmaf(ev, BH(u.x), acc[4]);               \
        acc[1] = fmaf(ev, BL(u.y), acc[1]);               \
        acc[5] = fmaf(ev, BH(u.y), acc[5]);               \
        acc[2] = fmaf(ev, BL(u.z), acc[2]);               \
        acc[6] = fmaf(ev, BH(u.z), acc[6]);               \
        acc[3] = fmaf(ev, BL(u.w), acc[3]);               \
        acc[7] = fmaf(ev, BH(u.w), acc[7]);

    int e = beg;
    for (; e + 8 <= end; e += 8) {
        unsigned int rr[8];
        uint4 u[8];
        #pragma unroll
        for (int i = 0; i < 8; ++i) rr[i] = erec[e + i];
        #pragma unroll
        for (int i = 0; i < 8; ++i)
            u[i] = hbu4[(size_t)(rr[i] >> 16) * 16 + l];
        #pragma unroll
        for (int i = 0; i < 8; ++i) {
            const float ev = __half2float(__ushort_as_half((unsigned short)(rr[i] & 0xffffu)));
            ACC4(u[i], ev);
            rs += ev;
        }
    }
    for (; e + 2 <= end; e += 2) {
        const unsigned int r0 = erec[e], r1 = erec[e + 1];
        const uint4 u0 = hbu4[(size_t)(r0 >> 16) * 16 + l];
        const uint4 u1 = hbu4[(size_t)(r1 >> 16) * 16 + l];
        const float e0 = __half2float(__ushort_as_half((unsigned short)(r0 & 0xffffu)));
        const float e1 = __half2float(__ushort_as_half((unsigned short)(r1 & 0xffffu)));
        ACC4(u0, e0); ACC4(u1, e1);
        rs += e0 + e1;
    }
    if (e < end) {
        const unsigned int r0 = erec[e];
        const uint4 u0 = hbu4[(size_t)(r0 >> 16) * 16 + l];
        const float e0 = __half2float(__ushort_as_half((unsigned short)(r0 & 0xffffu)));
        ACC4(u0, e0);
        rs += e0;
    }
    #undef ACC4

    const float rinv = 1.0f / (rs + 1e-16f);
    const uint4 us = hbu4[(size_t)node * 16 + l];   // node's own h row (bf16)
    float* op = out + (size_t)node * NHID + l;
    float z;
    z = BL(us.x) - acc[0] * rinv; op[0]   = (z > 0.f) ? z : (expf(z) - 1.f);
    z = BH(us.x) - acc[4] * rinv; op[16]  = (z > 0.f) ? z : (expf(z) - 1.f);
    z = BL(us.y) - acc[1] * rinv; op[32]  = (z > 0.f) ? z : (expf(z) - 1.f);
    z = BH(us.y) - acc[5] * rinv; op[48]  = (z > 0.f) ? z : (expf(z) - 1.f);
    z = BL(us.z) - acc[2] * rinv; op[64]  = (z > 0.f) ? z : (expf(z) - 1.f);
    z = BH(us.z) - acc[6] * rinv; op[80]  = (z > 0.f) ? z : (expf(z) - 1.f);
    z = BL(us.w) - acc[3] * rinv; op[96]  = (z > 0.f) ? z : (expf(z) - 1.f);
    z = BH(us.w) - acc[7] * rinv; op[112] = (z > 0.f) ? z : (expf(z) - 1.f);
    #undef BL
    #undef BH
}

// ---------------------------------------------------------------------------
extern "C" void kernel_launch(void* const* d_in, const int* in_sizes, int n_in,
                              void* d_out, int out_size, void* d_ws, size_t ws_size,
                              hipStream_t stream) {
    const float* x  = (const float*)d_in[0];
    const float* W  = (const float*)d_in[1];
    const float* a  = (const float*)d_in[2];
    const int*   ei = (const int*)d_in[3];

    const int n = in_sizes[0] / NFEAT;   // 50000
    const int E = in_sizes[3] / 2;       // 640000
    const int nb = (n + 255) / 256;      // 196 (<= 256)

    float* out = (float*)d_out;

    // Workspace (4-byte units):
    //   hbu[n*64] | s1[n] | s2[n] | erec[E] | Wtg[8192] |
    //   hist[n] | bsums[256] | row_ptr[n+1] | cursor[n]
    unsigned int* hbu    = (unsigned int*)d_ws;
    float*        s1     = (float*)(hbu + (size_t)n * 64);
    float*        s2     = s1 + n;
    unsigned int* erec   = (unsigned int*)(s2 + n);
    unsigned int* Wtg    = erec + E;
    int*          hist   = (int*)(Wtg + 8192);
    int*          bsums  = hist + n;
    int*          row_ptr = bsums + 256;
    int*          cursor  = row_ptr + (n + 1);

    // 1) W transpose + hist zero.
    prep_wt_kernel<<<16 + 50, 256, 0, stream>>>(W, Wtg, hist, n);

    // 2) GEMM + fused histogram (block-specialized).
    const int gemm_blocks = (n + 63) / 64;       // 782
    const int hist_blocks = 128;
    gemm_h_kernel<<<gemm_blocks + hist_blocks, 256, 0, stream>>>(
        x, Wtg, a, hbu, s1, s2, n, ei, hist, E, gemm_blocks);

    // 3) per-block scan, 4) fused level-2 scan + add (cursor init).
    scan_block_kernel<<<nb, 256, 0, stream>>>(hist, row_ptr, bsums, n);
    scan_add_kernel<<<nb, 256, 0, stream>>>(row_ptr, cursor, bsums, n, E, nb);

    // 5) scatter edges into CSR order with precomputed fp16 ev.
    scatter_kernel<<<(E + 255) / 256, 256, 0, stream>>>(ei, s1, s2, cursor, erec, E);

    // 6) gather-aggregate + finalize (reads hbu only).
    aggregate_kernel<<<((size_t)n * 16 + 255) / 256, 256, 0, stream>>>(
        row_ptr, erec, hbu, out, n);
}